// Round 1
// baseline (230.905 us; speedup 1.0000x reference)
//
#include <hip/hip_runtime.h>

#define B_ 2
#define NCAM_ 6
#define C_ 256
#define HF_ 64
#define WF_ 176
#define NX_ 200
#define NY_ 200
#define NZ_ 4
#define V_ (NX_*NY_*NZ_)      /* 160000 */
#define HW_ (HF_*WF_)         /* 11264 */
#define OUTC_ 80
#define NPOS_ (NX_*NY_)       /* 40000 */

/* workspace layout (float offsets) — total ~42.5 MiB */
#define WS_PROJ 0            /* 144 floats: [b][n][3][4] */
#define WS_IMGT 144          /* 24 floats: [b][n][2] */
#define WS_SCALE 256         /* 80 floats */
#define WS_SHIFT 336         /* 80 floats */
#define WS_IDX 512           /* 320000 ints: [b][v] */
#define WS_PF 320512         /* 12*11264*80 floats: [b*6+n][hw][o] */

// ---------------------------------------------------------------- K0: prep
__global__ void k0_prep(const float* __restrict__ l2i,
                        const float* __restrict__ img_aug,
                        float* __restrict__ ws)
{
    int t = threadIdx.x;
    if (t < B_*NCAM_*12) {
        int bn = t / 12;           // b*6+n
        int e  = t % 12;
        int i = e >> 2, j = e & 3;
        const float* A = img_aug + bn*16;
        const float* L = l2i + bn*16;
        float acc = 0.f;
        #pragma unroll
        for (int k = 0; k < 4; ++k) {
            float a = (k < 3) ? A[i*4 + k] : 0.f;   // img_r: column 3 zeroed
            acc = fmaf(a, L[k*4 + j], acc);
        }
        ws[WS_PROJ + t] = acc;
    }
    if (t >= 192 && t < 192 + B_*NCAM_*2) {
        int s = t - 192;
        int bn = s >> 1, i = s & 1;
        ws[WS_IMGT + s] = img_aug[bn*16 + i*4 + 3];
    }
}

// ------------------------------------------------------- K1: voxel -> cam idx
__global__ __launch_bounds__(256) void k1_project(const float* __restrict__ ws,
                                                  const float* __restrict__ lidar_aug,
                                                  int* __restrict__ idx)
{
    int gid = blockIdx.x*256 + threadIdx.x;
    if (gid >= B_*V_) return;
    int b = gid / V_;
    int v = gid - b*V_;
    int ixy = v >> 2;
    int iz  = v & 3;
    int ix = ixy / NY_;
    int iy = ixy - ix*NY_;
    float x = ix*0.5f - 50.f;
    float y = iy*0.5f - 50.f;
    float z = iz*1.5f - 4.f;

    const float* la = lidar_aug + b*16;
    float gx = x - la[3], gy = y - la[7], gz = z - la[11];
    // pts = lr.T @ (g - lt), sequential fma over k
    float px = fmaf(la[8],  gz, fmaf(la[4], gy, fmaf(la[0], gx, 0.f)));
    float py = fmaf(la[9],  gz, fmaf(la[5], gy, fmaf(la[1], gx, 0.f)));
    float pz = fmaf(la[10], gz, fmaf(la[6], gy, fmaf(la[2], gx, 0.f)));

    int best = -1;
    #pragma unroll
    for (int n = 0; n < NCAM_; ++n) {
        const float* P = ws + WS_PROJ + (b*NCAM_ + n)*12;
        float t0 = fmaf(P[3], 1.f, fmaf(P[2],  pz, fmaf(P[1], py, fmaf(P[0], px, 0.f))));
        float t1 = fmaf(P[7], 1.f, fmaf(P[6],  pz, fmaf(P[5], py, fmaf(P[4], px, 0.f))));
        float t2 = fmaf(P[11],1.f, fmaf(P[10], pz, fmaf(P[9], py, fmaf(P[8], px, 0.f))));
        float u = t0/t2 + ws[WS_IMGT + (b*NCAM_+n)*2 + 0];
        float w = t1/t2 + ws[WS_IMGT + (b*NCAM_+n)*2 + 1];
        int uf = (int)rintf(u*0.25f);   // /STRIDE(=4) is an exact scale
        int vf = (int)rintf(w*0.25f);
        if (uf >= 0 && vf >= 0 && uf < WF_ && vf < HF_ && t2 > 0.f)
            best = n*HW_ + vf*WF_ + uf;   // last valid camera wins
    }
    idx[gid] = best;
}

// -------------------------------------------- K2: pf[bn][hw][o] = W @ feat
__global__ __launch_bounds__(256) void k2_gemm(const float* __restrict__ feat,
                                               const float* __restrict__ w,
                                               float* __restrict__ pf)
{
    __shared__ float fs[32][64];
    __shared__ float wsd[80][36];
    __shared__ float os[64][84];
    int bn  = blockIdx.y;
    int hw0 = blockIdx.x*64;
    int tid = threadIdx.x;
    int tx = tid & 15, ty = tid >> 4;
    float acc[5][4] = {};
    const float* fb = feat + (size_t)bn*C_*HW_;

    for (int c0 = 0; c0 < C_; c0 += 32) {
        for (int l = tid; l < 512; l += 256) {
            int cc = l >> 4, p4 = (l & 15) << 2;
            *(float4*)&fs[cc][p4] = *(const float4*)&fb[(size_t)(c0+cc)*HW_ + hw0 + p4];
        }
        for (int l = tid; l < 640; l += 256) {
            int o = l >> 3, q = (l & 7) << 2;
            *(float4*)&wsd[o][q] = *(const float4*)&w[o*C_ + c0 + q];
        }
        __syncthreads();
        #pragma unroll
        for (int cc = 0; cc < 32; cc += 4) {
            float4 f0 = *(float4*)&fs[cc+0][tx<<2];
            float4 f1 = *(float4*)&fs[cc+1][tx<<2];
            float4 f2 = *(float4*)&fs[cc+2][tx<<2];
            float4 f3 = *(float4*)&fs[cc+3][tx<<2];
            #pragma unroll
            for (int j = 0; j < 5; ++j) {
                float4 wv = *(float4*)&wsd[ty*5+j][cc];
                acc[j][0] = fmaf(wv.x,f0.x, fmaf(wv.y,f1.x, fmaf(wv.z,f2.x, fmaf(wv.w,f3.x, acc[j][0]))));
                acc[j][1] = fmaf(wv.x,f0.y, fmaf(wv.y,f1.y, fmaf(wv.z,f2.y, fmaf(wv.w,f3.y, acc[j][1]))));
                acc[j][2] = fmaf(wv.x,f0.z, fmaf(wv.y,f1.z, fmaf(wv.z,f2.z, fmaf(wv.w,f3.z, acc[j][2]))));
                acc[j][3] = fmaf(wv.x,f0.w, fmaf(wv.y,f1.w, fmaf(wv.z,f2.w, fmaf(wv.w,f3.w, acc[j][3]))));
            }
        }
        __syncthreads();
    }
    #pragma unroll
    for (int j = 0; j < 5; ++j)
        #pragma unroll
        for (int p = 0; p < 4; ++p)
            os[tx*4+p][ty*5+j] = acc[j][p];
    __syncthreads();
    float* pb = pf + ((size_t)bn*HW_ + hw0)*80;
    for (int l = tid; l < 1280; l += 256) {
        int f = l << 2;
        int p = f / 80, o = f - p*80;
        *(float4*)&pb[f] = *(float4*)&os[p][o];
    }
}

// ----------------------------- K3: gather + z-weighted sum + bias -> y (d_out)
__global__ __launch_bounds__(320) void k3_gather(const int* __restrict__ idx,
                                                 const float* __restrict__ points,
                                                 const float* __restrict__ pf,
                                                 const float* __restrict__ conv_b,
                                                 float* __restrict__ y)
{
    __shared__ int   idx_s[256];
    __shared__ float w_s[256];
    __shared__ float y_s[OUTC_][65];
    int b = blockIdx.y;
    int tile = blockIdx.x;       // 0..624, 64 positions each
    int t = threadIdx.x;
    if (t < 256) {
        idx_s[t] = idx[b*V_ + tile*256 + t];          // [p][iz]
        int izl = t >> 6, p = t & 63;
        w_s[izl*64 + p] = points[b*V_ + izl*NPOS_ + tile*64 + p];
    }
    __syncthreads();
    int o  = t % 80;
    int pg = t / 80;             // 0..3
    float bias = conv_b[o];
    const float* pfb = pf + (size_t)b*(NCAM_*HW_)*80;
    for (int i = 0; i < 16; ++i) {
        int p = pg*16 + i;
        float acc = bias;
        #pragma unroll
        for (int iz = 0; iz < 4; ++iz) {
            int g = idx_s[p*4 + iz];
            if (g >= 0) acc = fmaf(w_s[iz*64 + p], pfb[(size_t)g*80 + o], acc);
        }
        y_s[o][p] = acc;
    }
    __syncthreads();
    float* yb = y + (size_t)b*OUTC_*NPOS_ + tile*64;
    for (int l = t; l < OUTC_*64; l += 320) {
        int oo = l >> 6, p = l & 63;
        yb[(size_t)oo*NPOS_ + p] = y_s[oo][p];
    }
}

// ------------------------------------------------ K4: per-channel BN stats
__global__ __launch_bounds__(256) void k4_stats(const float* __restrict__ y,
                                                const float* __restrict__ gamma,
                                                const float* __restrict__ beta,
                                                float* __restrict__ ws)
{
    int o = blockIdx.x;
    int t = threadIdx.x;
    float s1 = 0.f, s2 = 0.f;
    for (int b = 0; b < B_; ++b) {
        const float* yb = y + (size_t)(b*OUTC_ + o)*NPOS_;
        for (int j = t; j < NPOS_; j += 256) {
            float v = yb[j];
            s1 += v; s2 += v*v;
        }
    }
    __shared__ float r1[256], r2[256];
    r1[t] = s1; r2[t] = s2;
    __syncthreads();
    for (int s = 128; s > 0; s >>= 1) {
        if (t < s) { r1[t] += r1[t+s]; r2[t] += r2[t+s]; }
        __syncthreads();
    }
    if (t == 0) {
        const float invN = 1.f/(float)(B_*NPOS_);
        float mean = r1[0]*invN;
        float var  = r2[0]*invN - mean*mean;
        float inv  = rsqrtf(var + 1e-5f);
        float sc   = gamma[o]*inv;
        ws[WS_SCALE + o] = sc;
        ws[WS_SHIFT + o] = beta[o] - mean*sc;
    }
}

// --------------------------------------------- K5: affine + ReLU, in place
__global__ __launch_bounds__(256) void k5_norm(float* __restrict__ y,
                                               const float* __restrict__ ws)
{
    int gid = blockIdx.x*256 + threadIdx.x;
    int f = gid*4;
    if (f >= B_*OUTC_*NPOS_) return;
    int o = (f / NPOS_) % OUTC_;     // 40000 % 4 == 0, so whole float4 shares o
    float sc = ws[WS_SCALE + o], sh = ws[WS_SHIFT + o];
    float4 v = *(float4*)&y[f];
    v.x = fmaxf(fmaf(v.x, sc, sh), 0.f);
    v.y = fmaxf(fmaf(v.y, sc, sh), 0.f);
    v.z = fmaxf(fmaf(v.z, sc, sh), 0.f);
    v.w = fmaxf(fmaf(v.w, sc, sh), 0.f);
    *(float4*)&y[f] = v;
}

extern "C" void kernel_launch(void* const* d_in, const int* in_sizes, int n_in,
                              void* d_out, int out_size, void* d_ws, size_t ws_size,
                              hipStream_t stream) {
    (void)in_sizes; (void)n_in; (void)out_size; (void)ws_size;
    const float* feat      = (const float*)d_in[0];
    const float* points    = (const float*)d_in[1];
    const float* l2i       = (const float*)d_in[2];
    const float* img_aug   = (const float*)d_in[3];
    const float* lidar_aug = (const float*)d_in[4];
    const float* conv_w    = (const float*)d_in[5];
    const float* conv_b    = (const float*)d_in[6];
    const float* gamma     = (const float*)d_in[7];
    const float* beta      = (const float*)d_in[8];
    float* out = (float*)d_out;
    float* wsf = (float*)d_ws;
    int*   idx = (int*)(wsf + WS_IDX);
    float* pf  = wsf + WS_PF;

    hipLaunchKernelGGL(k0_prep, dim3(1), dim3(256), 0, stream, l2i, img_aug, wsf);
    hipLaunchKernelGGL(k1_project, dim3((B_*V_)/256), dim3(256), 0, stream, wsf, lidar_aug, idx);
    hipLaunchKernelGGL(k2_gemm, dim3(HW_/64, B_*NCAM_), dim3(256), 0, stream, feat, conv_w, pf);
    hipLaunchKernelGGL(k3_gather, dim3(NPOS_/64, B_), dim3(320), 0, stream, idx, points, pf, conv_b, out);
    hipLaunchKernelGGL(k4_stats, dim3(OUTC_), dim3(256), 0, stream, out, gamma, beta, wsf);
    hipLaunchKernelGGL(k5_norm, dim3((B_*OUTC_*NPOS_/4)/256), dim3(256), 0, stream, out, wsf);
}

// Round 3
// 122.366 us; speedup vs baseline: 1.8870x; 1.8870x over previous
//
#include <hip/hip_runtime.h>

#define B_ 2
#define NCAM_ 6
#define C_ 256
#define HF_ 64
#define WF_ 176
#define NX_ 200
#define NY_ 200
#define NZ_ 4
#define V_ (NX_*NY_*NZ_)      /* 160000 */
#define HW_ (HF_*WF_)         /* 11264 */
#define OUTC_ 80
#define NPOS_ (NX_*NY_)       /* 40000 */

typedef unsigned short u16;
typedef unsigned int   u32;
typedef __attribute__((ext_vector_type(8))) short bf16x8;
typedef __attribute__((ext_vector_type(4))) float f32x4;
typedef __attribute__((ext_vector_type(2))) unsigned int u32x2;

/* workspace layout (float offsets) */
#define WS_PROJ 0            /* 144: [b][n][3][4] */
#define WS_IMGT 144          /* 24:  [b][n][2] */
#define WS_SCALE 256         /* 80 */
#define WS_SHIFT 336         /* 80 */
#define WS_PART 416          /* 80*8*2 = 1280 partial sums */
#define WS_WB   2048         /* u16[80*256] = 10240 floats */
#define WS_IDX  16384        /* int[320000] */
#define WS_PF   336384       /* u16[12*11264*80] bf16 */

__device__ __forceinline__ u16 f2bf(float x) {
    u32 u = __float_as_uint(x);
    u32 r = (u + 0x7fffu + ((u >> 16) & 1u)) >> 16;   // RNE
    return (u16)r;
}
__device__ __forceinline__ float bf2f(u16 v) {
    return __uint_as_float(((u32)v) << 16);
}

// ---------------------------------------------------------------- K0: prep
__global__ void k0_prep(const float* __restrict__ l2i,
                        const float* __restrict__ img_aug,
                        const float* __restrict__ conv_w,
                        float* __restrict__ ws)
{
    int t = threadIdx.x;
    if (t < B_*NCAM_*12) {
        int bn = t / 12;
        int e  = t % 12;
        int i = e >> 2, j = e & 3;
        const float* A = img_aug + bn*16;
        const float* L = l2i + bn*16;
        float acc = 0.f;
        #pragma unroll
        for (int k = 0; k < 4; ++k) {
            float a = (k < 3) ? A[i*4 + k] : 0.f;   // img_r: column 3 zeroed
            acc = fmaf(a, L[k*4 + j], acc);
        }
        ws[WS_PROJ + t] = acc;
    }
    if (t >= 192 && t < 192 + B_*NCAM_*2) {
        int s = t - 192;
        int bn = s >> 1, i = s & 1;
        ws[WS_IMGT + s] = img_aug[bn*16 + i*4 + 3];
    }
    u16* wb = (u16*)(ws + WS_WB);
    for (int i = t; i < OUTC_*C_; i += 256) wb[i] = f2bf(conv_w[i]);
}

// ------------------------------------------------------- K1: voxel -> cam idx
__global__ __launch_bounds__(256) void k1_project(const float* __restrict__ ws,
                                                  const float* __restrict__ lidar_aug,
                                                  int* __restrict__ idx)
{
    int gid = blockIdx.x*256 + threadIdx.x;
    if (gid >= B_*V_) return;
    int b = gid / V_;
    int v = gid - b*V_;
    int ixy = v >> 2;
    int iz  = v & 3;
    int ix = ixy / NY_;
    int iy = ixy - ix*NY_;
    float x = ix*0.5f - 50.f;
    float y = iy*0.5f - 50.f;
    float z = iz*1.5f - 4.f;

    const float* la = lidar_aug + b*16;
    float gx = x - la[3], gy = y - la[7], gz = z - la[11];
    float px = fmaf(la[8],  gz, fmaf(la[4], gy, fmaf(la[0], gx, 0.f)));
    float py = fmaf(la[9],  gz, fmaf(la[5], gy, fmaf(la[1], gx, 0.f)));
    float pz = fmaf(la[10], gz, fmaf(la[6], gy, fmaf(la[2], gx, 0.f)));

    int best = -1;
    #pragma unroll
    for (int n = 0; n < NCAM_; ++n) {
        const float* P = ws + WS_PROJ + (b*NCAM_ + n)*12;
        float t0 = fmaf(P[3], 1.f, fmaf(P[2],  pz, fmaf(P[1], py, fmaf(P[0], px, 0.f))));
        float t1 = fmaf(P[7], 1.f, fmaf(P[6],  pz, fmaf(P[5], py, fmaf(P[4], px, 0.f))));
        float t2 = fmaf(P[11],1.f, fmaf(P[10], pz, fmaf(P[9], py, fmaf(P[8], px, 0.f))));
        float u = t0/t2 + ws[WS_IMGT + (b*NCAM_+n)*2 + 0];
        float w = t1/t2 + ws[WS_IMGT + (b*NCAM_+n)*2 + 1];
        int uf = (int)rintf(u*0.25f);
        int vf = (int)rintf(w*0.25f);
        if (uf >= 0 && vf >= 0 && uf < WF_ && vf < HF_ && t2 > 0.f)
            best = n*HW_ + vf*WF_ + uf;
    }
    idx[gid] = best;
}

// ---------------------------- K2: pf[bn][hw][o] = W @ feat  (bf16 MFMA)
// A = w_bf16 [o][c] (M=o), B = feat^T (K=c, N=hw). Per block: 256 hw, K=256.
// Shared K-packing g(hi,e) = (e>>2)*16 + hi*4 + (e&3) for both A and B.
__global__ __launch_bounds__(256) void k2_mfma(const float* __restrict__ feat,
                                               const u16* __restrict__ wb,
                                               u16* __restrict__ pf)
{
    __shared__ u16 lds[256][36];   // [hw][c] bf16, padded stride 36 (72B)
    const int bn  = blockIdx.y;
    const int hw0 = blockIdx.x*256;
    const int t   = threadIdx.x;
    const int wv  = t >> 6;
    const int l   = t & 63;
    const int la  = l & 15;
    const int hi  = l >> 4;

    const float* fb = feat + (size_t)bn*C_*HW_;
    const float* fcol = fb + hw0 + (t & 31);
    const int cq = t >> 5;          // 0..7

    f32x4 acc[4][5] = {};           // [hw-tile][o-tile]

    for (int ks = 0; ks < 8; ++ks) {
        const int c0 = ks*32;
        // ---- load 32 c x 256 hw chunk (each thread: 8 hw-groups x 4 c)
        float rv[8][4];
        #pragma unroll
        for (int it = 0; it < 8; ++it)
            #pragma unroll
            for (int j = 0; j < 4; ++j)
                rv[it][j] = fcol[(size_t)(c0 + cq*4 + j)*HW_ + it*32];
        __syncthreads();            // previous step's LDS reads complete
        #pragma unroll
        for (int it = 0; it < 8; ++it) {
            int hw = (t & 31) + it*32;
            u32 p0 = (u32)f2bf(rv[it][0]) | ((u32)f2bf(rv[it][1]) << 16);
            u32 p1 = (u32)f2bf(rv[it][2]) | ((u32)f2bf(rv[it][3]) << 16);
            u32x2 pk; pk.x = p0; pk.y = p1;
            *(u32x2*)&lds[hw][cq*4] = pk;
        }
        __syncthreads();            // writes visible
        // ---- A-fragments (5 o-tiles) from global bf16 w (L1/L2 resident)
        union { u32 u[4]; bf16x8 v; } A[5];
        #pragma unroll
        for (int u = 0; u < 5; ++u) {
            const u16* ap = wb + (size_t)(u*16 + la)*C_ + c0 + hi*4;
            u32x2 alo = *(const u32x2*)ap;
            u32x2 ahi = *(const u32x2*)(ap + 16);
            A[u].u[0] = alo.x; A[u].u[1] = alo.y;
            A[u].u[2] = ahi.x; A[u].u[3] = ahi.y;
        }
        // ---- B-fragment per hw-tile + MFMA
        #pragma unroll
        for (int tt = 0; tt < 4; ++tt) {
            int hw = (wv*4 + tt)*16 + la;
            union { u32 u[4]; bf16x8 v; } Bf;
            const u16* bp = &lds[hw][hi*4];
            u32x2 blo = *(const u32x2*)bp;
            u32x2 bhi = *(const u32x2*)(bp + 16);
            Bf.u[0] = blo.x; Bf.u[1] = blo.y;
            Bf.u[2] = bhi.x; Bf.u[3] = bhi.y;
            #pragma unroll
            for (int u = 0; u < 5; ++u)
                acc[tt][u] = __builtin_amdgcn_mfma_f32_16x16x32_bf16(A[u].v, Bf.v, acc[tt][u], 0, 0, 0);
        }
    }
    // ---- epilogue: D row = o = u*16 + hi*4 + r, col = hw = tile + la
    u16* pfb = pf + (size_t)bn*HW_*80;
    #pragma unroll
    for (int tt = 0; tt < 4; ++tt) {
        int hw = hw0 + (wv*4 + tt)*16 + la;
        #pragma unroll
        for (int u = 0; u < 5; ++u) {
            f32x4 a = acc[tt][u];
            u32 p0 = (u32)f2bf(a.x) | ((u32)f2bf(a.y) << 16);
            u32 p1 = (u32)f2bf(a.z) | ((u32)f2bf(a.w) << 16);
            u32x2 pk; pk.x = p0; pk.y = p1;
            *(u32x2*)&pfb[(size_t)hw*80 + u*16 + hi*4] = pk;
        }
    }
}

// ----------------------------- K3: gather + z-weighted sum + bias -> y (d_out)
__global__ __launch_bounds__(320) void k3_gather(const int* __restrict__ idx,
                                                 const float* __restrict__ points,
                                                 const u16* __restrict__ pf,
                                                 const float* __restrict__ conv_b,
                                                 float* __restrict__ y)
{
    __shared__ int   idx_s[256];
    __shared__ float w_s[256];
    __shared__ float y_s[OUTC_][65];
    int b = blockIdx.y;
    int tile = blockIdx.x;       // 64 positions each
    int t = threadIdx.x;
    if (t < 256) {
        idx_s[t] = idx[b*V_ + tile*256 + t];          // [p][iz]
        int izl = t >> 6, p = t & 63;
        w_s[izl*64 + p] = points[b*V_ + izl*NPOS_ + tile*64 + p];
    }
    __syncthreads();
    int o  = t % 80;
    int pg = t / 80;             // 0..3
    float bias = conv_b[o];
    const u16* pfb = pf + (size_t)b*(NCAM_*HW_)*80;
    for (int i = 0; i < 16; ++i) {
        int p = pg*16 + i;
        float acc = bias;
        #pragma unroll
        for (int iz = 0; iz < 4; ++iz) {
            int g = idx_s[p*4 + iz];
            if (g >= 0) acc = fmaf(w_s[iz*64 + p], bf2f(pfb[(size_t)g*80 + o]), acc);
        }
        y_s[o][p] = acc;
    }
    __syncthreads();
    float* yb = y + (size_t)b*OUTC_*NPOS_ + tile*64;
    for (int l = t; l < OUTC_*64; l += 320) {
        int oo = l >> 6, p = l & 63;
        yb[(size_t)oo*NPOS_ + p] = y_s[oo][p];
    }
}

// ---------------------------------- K4a: per-channel partial sums (80x8 blocks)
__global__ __launch_bounds__(256) void k4a_partial(const float* __restrict__ y,
                                                   float* __restrict__ part)
{
    int o = blockIdx.x, slab = blockIdx.y;
    int t = threadIdx.x;
    float s1 = 0.f, s2 = 0.f;
    for (int b = 0; b < B_; ++b) {
        const float* yb = y + (size_t)(b*OUTC_ + o)*NPOS_ + slab*5000;
        for (int j = t; j < 5000; j += 256) {
            float v = yb[j];
            s1 += v; s2 += v*v;
        }
    }
    __shared__ float r1[256], r2[256];
    r1[t] = s1; r2[t] = s2;
    __syncthreads();
    for (int s = 128; s > 0; s >>= 1) {
        if (t < s) { r1[t] += r1[t+s]; r2[t] += r2[t+s]; }
        __syncthreads();
    }
    if (t == 0) {
        part[(o*8 + slab)*2 + 0] = r1[0];
        part[(o*8 + slab)*2 + 1] = r2[0];
    }
}

// ---------------------------------- K4b: finalize scale/shift (1 block)
__global__ __launch_bounds__(256) void k4b_final(const float* __restrict__ part,
                                                 const float* __restrict__ gamma,
                                                 const float* __restrict__ beta,
                                                 float* __restrict__ ws)
{
    int o = threadIdx.x;
    if (o >= OUTC_) return;
    float s1 = 0.f, s2 = 0.f;
    #pragma unroll
    for (int s = 0; s < 8; ++s) {
        s1 += part[(o*8 + s)*2 + 0];
        s2 += part[(o*8 + s)*2 + 1];
    }
    const float invN = 1.f/(float)(B_*NPOS_);
    float mean = s1*invN;
    float var  = s2*invN - mean*mean;
    float inv  = rsqrtf(var + 1e-5f);
    float sc   = gamma[o]*inv;
    ws[WS_SCALE + o] = sc;
    ws[WS_SHIFT + o] = beta[o] - mean*sc;
}

// --------------------------------------------- K5: affine + ReLU, in place
__global__ __launch_bounds__(256) void k5_norm(float* __restrict__ y,
                                               const float* __restrict__ ws)
{
    int gid = blockIdx.x*256 + threadIdx.x;
    int f = gid*4;
    if (f >= B_*OUTC_*NPOS_) return;
    int o = (f / NPOS_) % OUTC_;
    float sc = ws[WS_SCALE + o], sh = ws[WS_SHIFT + o];
    float4 v = *(float4*)&y[f];
    v.x = fmaxf(fmaf(v.x, sc, sh), 0.f);
    v.y = fmaxf(fmaf(v.y, sc, sh), 0.f);
    v.z = fmaxf(fmaf(v.z, sc, sh), 0.f);
    v.w = fmaxf(fmaf(v.w, sc, sh), 0.f);
    *(float4*)&y[f] = v;
}

extern "C" void kernel_launch(void* const* d_in, const int* in_sizes, int n_in,
                              void* d_out, int out_size, void* d_ws, size_t ws_size,
                              hipStream_t stream) {
    (void)in_sizes; (void)n_in; (void)out_size; (void)ws_size;
    const float* feat      = (const float*)d_in[0];
    const float* points    = (const float*)d_in[1];
    const float* l2i       = (const float*)d_in[2];
    const float* img_aug   = (const float*)d_in[3];
    const float* lidar_aug = (const float*)d_in[4];
    const float* conv_w    = (const float*)d_in[5];
    const float* conv_b    = (const float*)d_in[6];
    const float* gamma     = (const float*)d_in[7];
    const float* beta      = (const float*)d_in[8];
    float* out = (float*)d_out;
    float* wsf = (float*)d_ws;
    int*   idx = (int*)(wsf + WS_IDX);
    u16*   wb  = (u16*)(wsf + WS_WB);
    u16*   pf  = (u16*)(wsf + WS_PF);
    float* part = wsf + WS_PART;

    hipLaunchKernelGGL(k0_prep, dim3(1), dim3(256), 0, stream, l2i, img_aug, conv_w, wsf);
    hipLaunchKernelGGL(k1_project, dim3((B_*V_)/256), dim3(256), 0, stream, wsf, lidar_aug, idx);
    hipLaunchKernelGGL(k2_mfma, dim3(HW_/256, B_*NCAM_), dim3(256), 0, stream, feat, wb, pf);
    hipLaunchKernelGGL(k3_gather, dim3(NPOS_/64, B_), dim3(320), 0, stream, idx, points, pf, conv_b, out);
    hipLaunchKernelGGL(k4a_partial, dim3(OUTC_, 8), dim3(256), 0, stream, out, part);
    hipLaunchKernelGGL(k4b_final, dim3(1), dim3(256), 0, stream, part, gamma, beta, wsf);
    hipLaunchKernelGGL(k5_norm, dim3((B_*OUTC_*NPOS_/4 + 255)/256), dim3(256), 0, stream, out, wsf);
}